// Round 1
// baseline (1756.750 us; speedup 1.0000x reference)
//
#include <hip/hip_runtime.h>

#define NSTEPS 10

__global__ void ic_init(const float* __restrict__ prior,
                        float* __restrict__ p, float* __restrict__ rp,
                        float* __restrict__ delta, int n) {
    int i = blockIdx.x * blockDim.x + threadIdx.x;
    if (i < n) {
        float pr = prior[i];
        p[i] = pr;
        rp[i] = 1.0f - pr;
        delta[i] = 0.0f;
    }
}

__global__ void ic_edges(const int* __restrict__ src, const int* __restrict__ dst,
                         const float* __restrict__ ep, const float* __restrict__ p,
                         float* __restrict__ delta, int E) {
    int i = blockIdx.x * blockDim.x + threadIdx.x;
    if (i < E) {
        float v = ep[i] * p[src[i]];
        atomicAdd(&delta[dst[i]], v);
    }
}

__global__ void ic_nodes(float* __restrict__ p, float* __restrict__ rp,
                         float* __restrict__ delta, float* __restrict__ out, int n) {
    int i = blockIdx.x * blockDim.x + threadIdx.x;
    if (i < n) {
        float d = delta[i];
        delta[i] = 0.0f;                 // reset for next step
        float rpi = rp[i];
        float pt = rpi * (1.0f - __expf(-d));
        float rpn = rpi * (1.0f - pt);
        p[i] = pt;
        rp[i] = rpn;
        out[i] = 1.0f - rpn;             // last step's write is the answer
    }
}

extern "C" void kernel_launch(void* const* d_in, const int* in_sizes, int n_in,
                              void* d_out, int out_size, void* d_ws, size_t ws_size,
                              hipStream_t stream) {
    const float* prior = (const float*)d_in[0];
    const int*   eidx  = (const int*)d_in[1];   // [2, E] int32 (jax x64 disabled)
    const float* ep    = (const float*)d_in[2];
    float* out = (float*)d_out;

    const int N = in_sizes[0];
    const int E = in_sizes[2];
    const int* src = eidx;
    const int* dst = eidx + E;

    float* delta = (float*)d_ws;
    float* p     = delta + N;
    float* rp    = p + N;

    const int BT = 256;
    const int nb_nodes = (N + BT - 1) / BT;
    const int nb_edges = (E + BT - 1) / BT;

    ic_init<<<nb_nodes, BT, 0, stream>>>(prior, p, rp, delta, N);
    for (int t = 0; t < NSTEPS; ++t) {
        ic_edges<<<nb_edges, BT, 0, stream>>>(src, dst, ep, p, delta, E);
        ic_nodes<<<nb_nodes, BT, 0, stream>>>(p, rp, delta, out, N);
    }
}

// Round 2
// 382.559 us; speedup vs baseline: 4.5921x; 4.5921x over previous
//
#include <hip/hip_runtime.h>

#define NSTEPS 10
#define KNODES 128          // nodes per bucket (dst >> 7)
#define PBLK   512          // partition blocks for hist/scatter

// ---------------- init ----------------
__global__ void k_init(const float* __restrict__ prior,
                       float* __restrict__ p, float* __restrict__ rp, int n) {
    int i = blockIdx.x * blockDim.x + threadIdx.x;
    if (i < n) { float v = prior[i]; p[i] = v; rp[i] = 1.0f - v; }
}

// ---------------- pass A: per-block LDS histogram of dst buckets ----------------
__global__ void k_hist(const int* __restrict__ dst, unsigned* __restrict__ histT,
                       int E, int B, int chunk) {
    extern __shared__ unsigned h[];
    for (int i = threadIdx.x; i < B; i += blockDim.x) h[i] = 0u;
    __syncthreads();
    int start = blockIdx.x * chunk;
    int end   = min(start + chunk, E);
    for (int e = start + threadIdx.x; e < end; e += blockDim.x)
        atomicAdd(&h[((unsigned)dst[e]) >> 7], 1u);
    __syncthreads();
    // bin-major layout: histT[bin * P + blk]
    for (int i = threadIdx.x; i < B; i += blockDim.x)
        histT[(size_t)i * gridDim.x + blockIdx.x] = h[i];
}

// ---------------- exclusive scan (3 kernels) over M = B*PBLK elements ----------------
__global__ void k_scan1(const unsigned* __restrict__ in, unsigned* __restrict__ out,
                        unsigned* __restrict__ sums, int M) {
    __shared__ unsigned ts[256];
    int tid = threadIdx.x;
    size_t gi = (size_t)blockIdx.x * 1024 + (size_t)tid * 4;
    uint4 v = make_uint4(0, 0, 0, 0);
    if (gi + 4 <= (size_t)M) v = *(const uint4*)(in + gi);
    else {
        if (gi + 0 < (size_t)M) v.x = in[gi + 0];
        if (gi + 1 < (size_t)M) v.y = in[gi + 1];
        if (gi + 2 < (size_t)M) v.z = in[gi + 2];
        if (gi + 3 < (size_t)M) v.w = in[gi + 3];
    }
    unsigned s = v.x + v.y + v.z + v.w;
    ts[tid] = s; __syncthreads();
    for (int off = 1; off < 256; off <<= 1) {
        unsigned t = (tid >= off) ? ts[tid - off] : 0u; __syncthreads();
        ts[tid] += t; __syncthreads();
    }
    unsigned excl = ts[tid] - s;
    if (tid == 255) sums[blockIdx.x] = ts[255];
    uint4 o;
    o.x = excl; o.y = excl + v.x; o.z = excl + v.x + v.y; o.w = excl + v.x + v.y + v.z;
    if (gi + 4 <= (size_t)M) *(uint4*)(out + gi) = o;
    else {
        if (gi + 0 < (size_t)M) out[gi + 0] = o.x;
        if (gi + 1 < (size_t)M) out[gi + 1] = o.y;
        if (gi + 2 < (size_t)M) out[gi + 2] = o.z;
        if (gi + 3 < (size_t)M) out[gi + 3] = o.w;
    }
}

__global__ void k_scan2(unsigned* __restrict__ sums, int n) {  // n <= 1024, in-place exclusive
    __shared__ unsigned ts[1024];
    int tid = threadIdx.x;
    unsigned v = (tid < n) ? sums[tid] : 0u;
    ts[tid] = v; __syncthreads();
    for (int off = 1; off < 1024; off <<= 1) {
        unsigned t = (tid >= off) ? ts[tid - off] : 0u; __syncthreads();
        ts[tid] += t; __syncthreads();
    }
    if (tid < n) sums[tid] = ts[tid] - v;
}

__global__ void k_scan3(unsigned* __restrict__ out, const unsigned* __restrict__ sums, int M) {
    size_t gi = (size_t)blockIdx.x * 1024 + (size_t)threadIdx.x * 4;
    unsigned add = sums[blockIdx.x];
    if (gi + 4 <= (size_t)M) {
        uint4 v = *(uint4*)(out + gi);
        v.x += add; v.y += add; v.z += add; v.w += add;
        *(uint4*)(out + gi) = v;
    } else {
        for (int k = 0; k < 4; ++k)
            if (gi + k < (size_t)M) out[gi + k] += add;
    }
}

// ---------------- pass C: scatter edges into bucket-grouped array (LDS cursors) ----------------
__global__ void k_scatter(const int* __restrict__ src, const int* __restrict__ dst,
                          const float* __restrict__ ep, const unsigned* __restrict__ scanT,
                          uint2* __restrict__ csr, int E, int B, int chunk) {
    extern __shared__ unsigned cur[];
    int P = gridDim.x;
    for (int i = threadIdx.x; i < B; i += blockDim.x)
        cur[i] = scanT[(size_t)i * P + blockIdx.x];
    __syncthreads();
    int start = blockIdx.x * chunk;
    int end   = min(start + chunk, E);
    for (int e = start + threadIdx.x; e < end; e += blockDim.x) {
        unsigned d   = (unsigned)dst[e];
        unsigned bin = d >> 7;
        unsigned pos = atomicAdd(&cur[bin], 1u);
        // pack: src in bits [0,17), dst_local (7b) in bits [17,24)
        csr[pos] = make_uint2((unsigned)src[e] | ((d & 127u) << 17),
                              __float_as_uint(ep[e]));
    }
}

// ---------------- fused step: LDS delta + node update, no global atomics ----------------
__global__ void k_step(const uint2* __restrict__ csr, const unsigned* __restrict__ scanT,
                       const float* __restrict__ p_in, float* __restrict__ p_out,
                       float* __restrict__ rp, float* __restrict__ out,
                       int E, int N, int B) {
    __shared__ float dl[KNODES];
    int b = blockIdx.x, tid = threadIdx.x;
    if (tid < KNODES) dl[tid] = 0.0f;
    __syncthreads();
    unsigned s = scanT[(size_t)b * PBLK];
    unsigned e = (b + 1 < B) ? scanT[(size_t)(b + 1) * PBLK] : (unsigned)E;
    for (unsigned i = s + tid; i < e; i += blockDim.x) {
        uint2 r = csr[i];
        float w = __uint_as_float(r.y);
        atomicAdd(&dl[r.x >> 17], w * p_in[r.x & 0x1FFFFu]);
    }
    __syncthreads();
    if (tid < KNODES) {
        int node = (b << 7) + tid;
        if (node < N) {
            float d  = dl[tid];
            float r0 = rp[node];
            float pt = r0 * (1.0f - expf(-d));
            float rn = r0 * (1.0f - pt);
            p_out[node] = pt;
            rp[node]    = rn;
            out[node]   = 1.0f - rn;
        }
    }
}

// ---------------- fallback (R1 atomic path) ----------------
__global__ void fb_init(const float* __restrict__ prior, float* __restrict__ p,
                        float* __restrict__ rp, float* __restrict__ delta, int n) {
    int i = blockIdx.x * blockDim.x + threadIdx.x;
    if (i < n) { float v = prior[i]; p[i] = v; rp[i] = 1.0f - v; delta[i] = 0.0f; }
}
__global__ void fb_edges(const int* __restrict__ src, const int* __restrict__ dst,
                         const float* __restrict__ ep, const float* __restrict__ p,
                         float* __restrict__ delta, int E) {
    int i = blockIdx.x * blockDim.x + threadIdx.x;
    if (i < E) atomicAdd(&delta[dst[i]], ep[i] * p[src[i]]);
}
__global__ void fb_nodes(float* __restrict__ p, float* __restrict__ rp,
                         float* __restrict__ delta, float* __restrict__ out, int n) {
    int i = blockIdx.x * blockDim.x + threadIdx.x;
    if (i < n) {
        float d = delta[i]; delta[i] = 0.0f;
        float r0 = rp[i];
        float pt = r0 * (1.0f - expf(-d));
        float rn = r0 * (1.0f - pt);
        p[i] = pt; rp[i] = rn; out[i] = 1.0f - rn;
    }
}

extern "C" void kernel_launch(void* const* d_in, const int* in_sizes, int n_in,
                              void* d_out, int out_size, void* d_ws, size_t ws_size,
                              hipStream_t stream) {
    const float* prior = (const float*)d_in[0];
    const int*   eidx  = (const int*)d_in[1];   // [2, E] int32 (jax x64 disabled)
    const float* ep    = (const float*)d_in[2];
    float* out = (float*)d_out;

    const int N = in_sizes[0];
    const int E = in_sizes[2];
    const int* src = eidx;
    const int* dst = eidx + E;

    const int B = (N + KNODES - 1) / KNODES;          // buckets
    const size_t M = (size_t)B * PBLK;                // block-histogram elements
    const int chunks = (int)((M + 1023) / 1024);      // scan chunks (must be <= 1024)
    const int chunk  = (E + PBLK - 1) / PBLK;         // edges per partition block

    // carve workspace
    char* w = (char*)d_ws;
    auto carve = [&](size_t bytes) -> void* {
        void* r = (void*)w;
        w += (bytes + 255) & ~(size_t)255;
        return r;
    };
    float*    p0    = (float*)carve((size_t)N * 4);
    float*    p1    = (float*)carve((size_t)N * 4);
    float*    rp    = (float*)carve((size_t)N * 4);
    unsigned* histT = (unsigned*)carve(M * 4);
    unsigned* scanT = (unsigned*)carve(M * 4);
    unsigned* sums  = (unsigned*)carve((size_t)chunks * 4);
    uint2*    csr   = (uint2*)carve((size_t)E * 8);
    size_t need = (size_t)(w - (char*)d_ws);

    if (need <= ws_size && chunks <= 1024) {
        const int BT = 256;
        k_init<<<(N + BT - 1) / BT, BT, 0, stream>>>(prior, p0, rp, N);
        k_hist<<<PBLK, BT, B * 4, stream>>>(dst, histT, E, B, chunk);
        k_scan1<<<chunks, 256, 0, stream>>>(histT, scanT, sums, (int)M);
        k_scan2<<<1, 1024, 0, stream>>>(sums, chunks);
        k_scan3<<<chunks, 256, 0, stream>>>(scanT, sums, (int)M);
        k_scatter<<<PBLK, BT, B * 4, stream>>>(src, dst, ep, scanT, csr, E, B, chunk);
        float* pin = p0; float* pout = p1;
        for (int t = 0; t < NSTEPS; ++t) {
            k_step<<<B, BT, 0, stream>>>(csr, scanT, pin, pout, rp, out, E, N, B);
            float* tmp = pin; pin = pout; pout = tmp;
        }
    } else {
        // fallback: R1 global-atomic path (needs only ~1.2 MB ws)
        float* delta = (float*)d_ws;
        float* p     = delta + N;
        float* rpf   = p + N;
        const int BT = 256;
        fb_init<<<(N + BT - 1) / BT, BT, 0, stream>>>(prior, p, rpf, delta, N);
        for (int t = 0; t < NSTEPS; ++t) {
            fb_edges<<<(E + BT - 1) / BT, BT, 0, stream>>>(src, dst, ep, p, delta, E);
            fb_nodes<<<(N + BT - 1) / BT, BT, 0, stream>>>(p, rpf, delta, out, N);
        }
    }
}